// Round 6
// baseline (142.702 us; speedup 1.0000x reference)
//
#include <hip/hip_runtime.h>

// Qatten forward:
//   M[h,u,s] = sum_e W_key[h,e,u]*W_sel[h,e,s]        (kprep, LDS-tiled)
//   panel row p (400 rows, bf16, K-tile-blocked UNSWIZZLED in Wp[kt][p][32]):
//     p = h*64+u (u<64): M[h,u,:];  256+h: M[h,64,:];  264+e: Wv1[e,:];
//     392+h: Wh[h,:];  260-263,396-399: zero
//   kmain (512 thr, 8 waves): C = states x panel^T via 16x16x32 bf16 MFMA
//     INTRINSIC (compiler handles VALU->MFMA hazards; R5's inline-asm MFMA
//     read VALU-written operands with no wait states -> NaN).
//     NO LDS staging, NO barriers in the K loop: waves load A straight from
//     states (f32->bf16 inline, L1-reused 8x within block) and B straight
//     from the L2-resident panel. LDS only holds the C redistribution tile.

typedef unsigned short u16;
typedef unsigned int u32;
typedef float f32x4 __attribute__((ext_vector_type(4)));
typedef short s16x8 __attribute__((ext_vector_type(8)));
typedef unsigned int u32x4 __attribute__((ext_vector_type(4)));
typedef unsigned int u32x2 __attribute__((ext_vector_type(2)));

#define NEGV -99999999.0f
#define CSTRIDE 424   // u16; 212 words = 20 mod 32 -> 8 rows land on 8 banks

__device__ __forceinline__ u16 f2bf(float f) {
  union { float f; u32 u; } v; v.f = f;
  u32 r = v.u + 0x7fffu + ((v.u >> 16) & 1u);
  return (u16)(r >> 16);
}
__device__ __forceinline__ float bfl(u32 w) { union { u32 u; float f; } v; v.u = w << 16; return v.f; }
__device__ __forceinline__ float bfh(u32 w) { union { u32 u; float f; } v; v.u = w & 0xffff0000u; return v.f; }

// panel element (row p, col s) -> Wp[kt][p][s&31], plain layout
__device__ __forceinline__ void panel_store(u16* Wp, int p, int s, float v) {
  Wp[(s >> 5) * 12800 + p * 32 + (s & 31)] = f2bf(v);
}

// ---------------- kprep ------------------------------------------------------
__global__ __launch_bounds__(256) void kprep(
    const float* __restrict__ Wsel, const float* __restrict__ Wkey,
    const float* __restrict__ Wv1, const float* __restrict__ Wh,
    u16* __restrict__ Wp, float* __restrict__ accs) {
  const int bid = blockIdx.x, t = threadIdx.x;
  if (bid < 128) {
    __shared__ float wsS[2048];   // [e][16]
    __shared__ float wkS[8320];   // [e][65]
    const int h = bid >> 5, s0 = (bid & 31) << 4;
    for (int i = t; i < 2048; i += 256)
      wsS[i] = Wsel[((size_t)h * 128 + (i >> 4)) * 512 + s0 + (i & 15)];
    for (int i = t; i < 8320; i += 256)
      wkS[i] = Wkey[(size_t)h * 8320 + i];
    __syncthreads();
    {
      const int u = t >> 2, sl0 = (t & 3) << 2;
      float a0 = 0.f, a1 = 0.f, a2 = 0.f, a3 = 0.f;
      for (int e = 0; e < 128; ++e) {
        const float k = wkS[e * 65 + u];
        const float* wr = wsS + e * 16 + sl0;
        a0 = fmaf(k, wr[0], a0); a1 = fmaf(k, wr[1], a1);
        a2 = fmaf(k, wr[2], a2); a3 = fmaf(k, wr[3], a3);
      }
      const int p = h * 64 + u, s = s0 + sl0;
      panel_store(Wp, p, s, a0);     panel_store(Wp, p, s + 1, a1);
      panel_store(Wp, p, s + 2, a2); panel_store(Wp, p, s + 3, a3);
    }
    if (t < 16) {  // u = 64 row
      float a = 0.f;
      for (int e = 0; e < 128; ++e)
        a = fmaf(wkS[e * 65 + 64], wsS[e * 16 + t], a);
      panel_store(Wp, 256 + h, s0 + t, a);
    }
  } else {
    if (bid == 128 && t < 16) accs[t] = 0.f;
    for (int row = 260 + (bid - 128); row < 400; row += 8) {
      for (int s = t; s < 512; s += 256) {
        float v = 0.f;
        if (row >= 264 && row < 392) v = Wv1[(row - 264) * 512 + s];
        else if (row >= 392 && row < 396) v = Wh[(row - 392) * 512 + s];
        panel_store(Wp, row, s, v);
      }
    }
  }
}

// ---------------- kmain ------------------------------------------------------
__global__ __launch_bounds__(512, 4) void kmain(
    const float* __restrict__ states, const float* __restrict__ agent_qs,
    const int* __restrict__ actions, const u16* __restrict__ Wp,
    const float* __restrict__ bv1, const float* __restrict__ Wv2,
    const float* __restrict__ bv2, const float* __restrict__ bh,
    float* __restrict__ out, float* __restrict__ accs) {
  // LDS: only Ctile [64][CSTRIDE] u16 (54272B) + red (160B)
  __shared__ __align__(16) unsigned char smem[54272 + 160];
  u16* const Ctile = (u16*)smem;
  float* const red = (float*)(smem + 54272);

  const int tid = threadIdx.x;
  const int wid = tid >> 6;
  const int lane = tid & 63;
  const int c16 = lane & 15, sq = lane >> 4;
  const int b0 = blockIdx.x * 64;

  const f32x4 zf = {0.f, 0.f, 0.f, 0.f};
  f32x4 acc[4][4];
#pragma unroll
  for (int r = 0; r < 4; ++r)
#pragma unroll
    for (int i = 0; i < 4; ++i) acc[r][i] = zf;

  // A: lane (c16,sq) of rowfrag r reads states[(b0+r*16+c16)*512 + kt*32+sq*8]
  const float* aP[4];
#pragma unroll
  for (int r = 0; r < 4; ++r)
    aP[r] = states + (size_t)(b0 + r * 16 + c16) * 512 + sq * 8;
  // B: lane of colfrag f=wid+8i reads Wp[kt*12800 + (f*16+c16)*32 + sq*8]
  const u16* bP[4];
#pragma unroll
  for (int i = 0; i < 4; ++i) {
    const int f = wid + (i << 3);
    bP[i] = Wp + ((f < 25 ? f : 0) * 16 + c16) * 32 + sq * 8;
  }

#pragma unroll 2
  for (int kt = 0; kt < 16; ++kt) {
    s16x8 bfr[4];
#pragma unroll
    for (int i = 0; i < 4; ++i)
      if (wid + (i << 3) < 25)
        bfr[i] = *(const s16x8*)(bP[i] + kt * 12800);
    s16x8 af[4];
#pragma unroll
    for (int r = 0; r < 4; ++r) {
      const float* p = aP[r] + kt * 32;
      float4 x0 = *(const float4*)(p);
      float4 x1 = *(const float4*)(p + 4);
      af[r][0] = (short)f2bf(x0.x); af[r][1] = (short)f2bf(x0.y);
      af[r][2] = (short)f2bf(x0.z); af[r][3] = (short)f2bf(x0.w);
      af[r][4] = (short)f2bf(x1.x); af[r][5] = (short)f2bf(x1.y);
      af[r][6] = (short)f2bf(x1.z); af[r][7] = (short)f2bf(x1.w);
    }
#pragma unroll
    for (int i = 0; i < 4; ++i)
      if (wid + (i << 3) < 25) {
#pragma unroll
        for (int r = 0; r < 4; ++r)
          acc[r][i] = __builtin_amdgcn_mfma_f32_16x16x32_bf16(
              af[r], bfr[i], acc[r][i], 0, 0, 0);
      }
  }

  // spill acc to Ctile (bf16); intrinsic MFMA -> compiler handles hazards
#pragma unroll
  for (int r = 0; r < 4; ++r)
#pragma unroll
    for (int i = 0; i < 4; ++i) {
      const int f = wid + (i << 3);
      if (f < 25) {
        const int col = (f << 4) + c16;
        const int rowb = (r << 4) + (sq << 2);
#pragma unroll
        for (int j = 0; j < 4; ++j)
          Ctile[(rowb + j) * CSTRIDE + col] = f2bf(acc[r][i][j]);
      }
    }
  __syncthreads();

  // ---------------- epilogue: 8-lane group per row ----------------
  const int r = (wid << 3) + (lane >> 3);  // 0..63
  const int q8 = lane & 7;
  const int b = b0 + r;
  const u16* crow = Ctile + r * CSTRIDE;
  const float* srow = states + (size_t)b * 512;

  float m[4][8];
#pragma unroll
  for (int h = 0; h < 4; ++h) {
    u32x4 w = *(const u32x4*)(crow + h * 64 + q8 * 8);
#pragma unroll
    for (int k = 0; k < 4; ++k) {
      m[h][2 * k] = bfl(w[k]); m[h][2 * k + 1] = bfh(w[k]);
    }
  }

  float lp[4][8];
#pragma unroll
  for (int h = 0; h < 4; ++h)
#pragma unroll
    for (int a = 0; a < 8; ++a) lp[h][a] = 0.f;

#pragma unroll
  for (int a = 0; a < 8; ++a) {
    const float* xp = srow + a * 64 + q8 * 8;
    float4 v0 = *(const float4*)(xp);
    float4 v1 = *(const float4*)(xp + 4);
    float xv[8] = {v0.x, v0.y, v0.z, v0.w, v1.x, v1.y, v1.z, v1.w};
#pragma unroll
    for (int h = 0; h < 4; ++h) {
      float s = 0.f;
#pragma unroll
      for (int j = 0; j < 8; ++j) s = fmaf(m[h][j], xv[j], s);
      lp[h][a] = s;
    }
  }
#pragma unroll
  for (int h = 0; h < 4; ++h)
#pragma unroll
    for (int a = 0; a < 8; ++a) {
      float v = lp[h][a];
      v += __shfl_xor(v, 1, 64);
      v += __shfl_xor(v, 2, 64);
      v += __shfl_xor(v, 4, 64);
      lp[h][a] = v;
    }
  // u=64 term (agent_qs)
  float4 q0 = *(const float4*)(agent_qs + (size_t)b * 8);
  float4 q1 = *(const float4*)(agent_qs + (size_t)b * 8 + 4);
  float qv[8] = {q0.x, q0.y, q0.z, q0.w, q1.x, q1.y, q1.z, q1.w};
  u32x2 w64 = *(const u32x2*)(crow + 256);
  float m64[4] = {bfl(w64[0]), bfh(w64[0]), bfl(w64[1]), bfh(w64[1])};
#pragma unroll
  for (int h = 0; h < 4; ++h)
#pragma unroll
    for (int a = 0; a < 8; ++a) lp[h][a] = fmaf(m64[h], qv[a], lp[h][a]);

  float magp = 0.f;
  if (q8 == 0) {
#pragma unroll
    for (int h = 0; h < 4; ++h)
#pragma unroll
      for (int a = 0; a < 8; ++a) magp = fmaf(lp[h][a], lp[h][a], magp);
  }
  // v partial: 16 e per lane
  float bvv[16], wvv[16], cv[16];
#pragma unroll
  for (int g = 0; g < 4; ++g) {
    *(float4*)(bvv + g * 4) = *(const float4*)(bv1 + q8 * 16 + g * 4);
    *(float4*)(wvv + g * 4) = *(const float4*)(Wv2 + q8 * 16 + g * 4);
  }
#pragma unroll
  for (int g = 0; g < 2; ++g) {
    u32x4 wv = *(const u32x4*)(crow + 264 + q8 * 16 + g * 8);
#pragma unroll
    for (int k = 0; k < 4; ++k) {
      cv[g * 8 + 2 * k] = bfl(wv[k]); cv[g * 8 + 2 * k + 1] = bfh(wv[k]);
    }
  }
  float vp = 0.f;
#pragma unroll
  for (int e2 = 0; e2 < 16; ++e2)
    vp = fmaf(fmaxf(cv[e2] + bvv[e2], 0.f), wvv[e2], vp);
  vp += __shfl_xor(vp, 1, 64);
  vp += __shfl_xor(vp, 2, 64);
  vp += __shfl_xor(vp, 4, 64);

  int av[8];
  const int* ap = actions + (size_t)b * 8;
#pragma unroll
  for (int a = 0; a < 8; ++a) av[a] = ap[a];

  u32x2 ww = *(const u32x2*)(crow + 392);
  float whr[4] = {bfl(ww[0]), bfh(ww[0]), bfl(ww[1]), bfh(ww[1])};
  float4 bh4 = *(const float4*)(bh);
  float bhv[4] = {bh4.x, bh4.y, bh4.z, bh4.w};

  const float scale = 0.088388347648318447f;  // 1/sqrt(128)
  float att[8];
#pragma unroll
  for (int a = 0; a < 8; ++a) att[a] = 0.f;
  float entp[4];
#pragma unroll
  for (int h = 0; h < 4; ++h) {
    float whv = fabsf(whr[h] + bhv[h]);
    float sc[8];
#pragma unroll
    for (int a = 0; a < 8; ++a)
      sc[a] = (av[a] == 0) ? NEGV : lp[h][a] * scale;
    float mx = sc[0];
#pragma unroll
    for (int a = 1; a < 8; ++a) mx = fmaxf(mx, sc[a]);
    float ex[8];
    float sum = 0.f;
#pragma unroll
    for (int a = 0; a < 8; ++a) { ex[a] = __expf(sc[a] - mx); sum += ex[a]; }
    float inv = 1.f / sum;
    float ent = 0.f;
#pragma unroll
    for (int a = 0; a < 8; ++a) {
      float w = ex[a] * inv;
      att[a] = fmaf(w, whv, att[a]);
      ent = fmaf(w, __logf(w + 1e-8f), ent);
    }
    entp[h] = ent;
  }

  if (q8 == 0) {
    float4 o0 = {att[0], att[1], att[2], att[3]};
    float4 o1 = {att[4], att[5], att[6], att[7]};
    *(float4*)(out + (size_t)b * 8) = o0;
    *(float4*)(out + (size_t)b * 8 + 4) = o1;
    out[262144 + b] = vp + bv2[0];
  }

  float r0 = magp;
  float r1 = (q8 == 0) ? entp[0] : 0.f;
  float r2 = (q8 == 0) ? entp[1] : 0.f;
  float r3 = (q8 == 0) ? entp[2] : 0.f;
  float r4 = (q8 == 0) ? entp[3] : 0.f;
#pragma unroll
  for (int off = 1; off < 64; off <<= 1) {
    r0 += __shfl_xor(r0, off, 64);
    r1 += __shfl_xor(r1, off, 64);
    r2 += __shfl_xor(r2, off, 64);
    r3 += __shfl_xor(r3, off, 64);
    r4 += __shfl_xor(r4, off, 64);
  }
  if (lane == 0) {
    red[wid * 5 + 0] = r0; red[wid * 5 + 1] = r1; red[wid * 5 + 2] = r2;
    red[wid * 5 + 3] = r3; red[wid * 5 + 4] = r4;
  }
  __syncthreads();
  if (tid < 5) {
    float s = 0.f;
#pragma unroll
    for (int w = 0; w < 8; ++w) s += red[w * 5 + tid];
    atomicAdd(&accs[tid], s);
  }
  __syncthreads();  // block's atomics retired before counting
  if (tid == 0) {
    u32* cnt = (u32*)(accs + 8);
    if (atomicAdd(cnt, 1u) == 511u) {  // last block finalizes
      float a0 = atomicAdd(&accs[0], 0.f);
      float a1 = atomicAdd(&accs[1], 0.f);
      float a2 = atomicAdd(&accs[2], 0.f);
      float a3 = atomicAdd(&accs[3], 0.f);
      float a4 = atomicAdd(&accs[4], 0.f);
      out[294912] = 0.001f * a0 * (1.0f / 262144.0f);
      out[294913] = -a1 * (1.0f / 32768.0f);
      out[294914] = -a2 * (1.0f / 32768.0f);
      out[294915] = -a3 * (1.0f / 32768.0f);
      out[294916] = -a4 * (1.0f / 32768.0f);
    }
  }
}

extern "C" void kernel_launch(void* const* d_in, const int* in_sizes, int n_in,
                              void* d_out, int out_size, void* d_ws, size_t ws_size,
                              hipStream_t stream) {
  const float* agent_qs = (const float*)d_in[0];
  const float* states   = (const float*)d_in[1];
  const int*   actions  = (const int*)d_in[2];
  const float* Wsel = (const float*)d_in[3];
  const float* Wkey = (const float*)d_in[4];
  const float* Wv1  = (const float*)d_in[5];
  const float* bv1  = (const float*)d_in[6];
  const float* Wv2  = (const float*)d_in[7];
  const float* bv2  = (const float*)d_in[8];
  const float* Wh   = (const float*)d_in[9];
  const float* bh   = (const float*)d_in[10];
  float* out = (float*)d_out;
  float* accs = (float*)d_ws;                    // 16 floats (incl. counter)
  u16* Wp = (u16*)((char*)d_ws + 64);            // 16 tiles x 400 x 32 bf16

  hipLaunchKernelGGL(kprep, dim3(136), dim3(256), 0, stream,
                     Wsel, Wkey, Wv1, Wh, Wp, accs);
  hipLaunchKernelGGL(kmain, dim3(512), dim3(512), 0, stream,
                     states, agent_qs, actions, Wp, bv1, Wv2, bv2, bh, out, accs);
}

// Round 7
// 109.690 us; speedup vs baseline: 1.3010x; 1.3010x over previous
//
#include <hip/hip_runtime.h>

// Qatten forward:
//   M[h,u,s] = sum_e W_key[h,e,u]*W_sel[h,e,s]        (kprep, LDS-tiled)
//   panel row p (400 rows, bf16, K-tile-blocked in Wp[kt][p][32]):
//     p = h*64+u (u<64): M[h,u,:];  256+h: M[h,64,:];  264+e: Wv1[e,:];
//     392+h: Wh[h,:];  260-263,396-399: zero
//   kmain (256 thr, 4 waves, 3 blocks/CU): C = states x panel^T, 16x16x32
//     bf16 MFMA intrinsic. A staged in LDS (coalesced + swizzled, dbuf 2x4KB);
//     B read DIRECT from L2-resident panel into regs (1KB contiguous per
//     colfrag load -> perfect coalescing, no LDS, no staging barrier cost).
//     LDS high-water = Ctile (54.4KB) -> 3 blocks/CU.

typedef unsigned short u16;
typedef unsigned int u32;
typedef float f32x4 __attribute__((ext_vector_type(4)));
typedef short s16x8 __attribute__((ext_vector_type(8)));
typedef unsigned int u32x4 __attribute__((ext_vector_type(4)));
typedef unsigned int u32x2 __attribute__((ext_vector_type(2)));

#define NEGV -99999999.0f
#define CSTRIDE 424   // u16; 212 words = 20 mod 32 -> adjacent rows offset banks

__device__ __forceinline__ u16 f2bf(float f) {
  union { float f; u32 u; } v; v.f = f;
  u32 r = v.u + 0x7fffu + ((v.u >> 16) & 1u);
  return (u16)(r >> 16);
}
__device__ __forceinline__ float bfl(u32 w) { union { u32 u; float f; } v; v.u = w << 16; return v.f; }
__device__ __forceinline__ float bfh(u32 w) { union { u32 u; float f; } v; v.u = w & 0xffff0000u; return v.f; }

// panel element (row p, col s) -> Wp[kt][p][s&31], plain layout
__device__ __forceinline__ void panel_store(u16* Wp, int p, int s, float v) {
  Wp[(s >> 5) * 12800 + p * 32 + (s & 31)] = f2bf(v);
}

// ---------------- kprep ------------------------------------------------------
__global__ __launch_bounds__(256) void kprep(
    const float* __restrict__ Wsel, const float* __restrict__ Wkey,
    const float* __restrict__ Wv1, const float* __restrict__ Wh,
    u16* __restrict__ Wp, float* __restrict__ accs) {
  const int bid = blockIdx.x, t = threadIdx.x;
  if (bid < 128) {
    __shared__ float wsS[2048];   // [e][16]
    __shared__ float wkS[8320];   // [e][65]
    const int h = bid >> 5, s0 = (bid & 31) << 4;
    for (int i = t; i < 2048; i += 256)
      wsS[i] = Wsel[((size_t)h * 128 + (i >> 4)) * 512 + s0 + (i & 15)];
    for (int i = t; i < 8320; i += 256)
      wkS[i] = Wkey[(size_t)h * 8320 + i];
    __syncthreads();
    {
      const int u = t >> 2, sl0 = (t & 3) << 2;
      float a0 = 0.f, a1 = 0.f, a2 = 0.f, a3 = 0.f;
      for (int e = 0; e < 128; ++e) {
        const float k = wkS[e * 65 + u];
        const float* wr = wsS + e * 16 + sl0;
        a0 = fmaf(k, wr[0], a0); a1 = fmaf(k, wr[1], a1);
        a2 = fmaf(k, wr[2], a2); a3 = fmaf(k, wr[3], a3);
      }
      const int p = h * 64 + u, s = s0 + sl0;
      panel_store(Wp, p, s, a0);     panel_store(Wp, p, s + 1, a1);
      panel_store(Wp, p, s + 2, a2); panel_store(Wp, p, s + 3, a3);
    }
    if (t < 16) {  // u = 64 row
      float a = 0.f;
      for (int e = 0; e < 128; ++e)
        a = fmaf(wkS[e * 65 + 64], wsS[e * 16 + t], a);
      panel_store(Wp, 256 + h, s0 + t, a);
    }
  } else {
    if (bid == 128 && t < 16) accs[t] = 0.f;
    for (int row = 260 + (bid - 128); row < 400; row += 8) {
      for (int s = t; s < 512; s += 256) {
        float v = 0.f;
        if (row >= 264 && row < 392) v = Wv1[(row - 264) * 512 + s];
        else if (row >= 392 && row < 396) v = Wh[(row - 392) * 512 + s];
        panel_store(Wp, row, s, v);
      }
    }
  }
}

// ---------------- kmain ------------------------------------------------------
__device__ __forceinline__ void stageA(unsigned char* dst, const float4& x0, const float4& x1) {
  u32x4 aw;
  aw[0] = (u32)f2bf(x0.x) | ((u32)f2bf(x0.y) << 16);
  aw[1] = (u32)f2bf(x0.z) | ((u32)f2bf(x0.w) << 16);
  aw[2] = (u32)f2bf(x1.x) | ((u32)f2bf(x1.y) << 16);
  aw[3] = (u32)f2bf(x1.z) | ((u32)f2bf(x1.w) << 16);
  *(u32x4*)dst = aw;
}

__device__ __forceinline__ void computeT(const unsigned char* buf, int kt,
                                         const u16* const bQ[7], int wid,
                                         int c16, int slot, f32x4 acc[4][7]) {
  s16x8 af[4];
#pragma unroll
  for (int r = 0; r < 4; ++r)
    af[r] = *(const s16x8*)(buf + (r * 16 + c16) * 64 + slot * 16);
#pragma unroll
  for (int i = 0; i < 7; ++i) {
    const int f = wid + (i << 2);
    if (f < 25) {
      s16x8 bfr = *(const s16x8*)(bQ[i] + kt * 12800);
#pragma unroll
      for (int r = 0; r < 4; ++r)
        acc[r][i] = __builtin_amdgcn_mfma_f32_16x16x32_bf16(
            af[r], bfr, acc[r][i], 0, 0, 0);
    }
  }
}

__global__ __launch_bounds__(256, 3) void kmain(
    const float* __restrict__ states, const float* __restrict__ agent_qs,
    const int* __restrict__ actions, const u16* __restrict__ Wp,
    const float* __restrict__ bv1, const float* __restrict__ Wv2,
    const float* __restrict__ bv2, const float* __restrict__ bh,
    float* __restrict__ out, float* __restrict__ accs) {
  // LDS: A dbuf 2x4KB @0/@4096; Ctile [64][CSTRIDE] u16 (54272B) reuses space;
  // red (80B) after. High-water 54432B -> 3 blocks/CU.
  __shared__ __align__(16) unsigned char smem[54272 + 80];
  unsigned char* const buf0 = smem;
  unsigned char* const buf1 = smem + 4096;
  u16* const Ctile = (u16*)smem;
  float* const red = (float*)(smem + 54272);

  const int tid = threadIdx.x;
  const int wid = tid >> 6;
  const int lane = tid & 63;
  const int c16 = lane & 15, sq = lane >> 4;
  const int slot = sq ^ ((c16 >> 1) & 3);
  const int b0 = blockIdx.x * 64;

  const f32x4 zf = {0.f, 0.f, 0.f, 0.f};
  f32x4 acc[4][7];
#pragma unroll
  for (int r = 0; r < 4; ++r)
#pragma unroll
    for (int i = 0; i < 7; ++i) acc[r][i] = zf;

  // A staging: 256 thr x 32B (fp32) -> bf16 16B, swizzled into [64][64B]
  const int ar = tid >> 2, ac = tid & 3;
  const float* aG = states + (size_t)(b0 + ar) * 512 + ac * 8;
  const int aWoff = ar * 64 + ((ac ^ ((ar >> 1) & 3)) << 4);

  // B: colfrag f = wid + 4i; lane reads Wp[kt][f*16+c16][sq*8..+8] (1KB/wave)
  const u16* bQ[7];
#pragma unroll
  for (int i = 0; i < 7; ++i) {
    const int f = wid + (i << 2);
    bQ[i] = Wp + ((f < 25 ? f : 0) * 16 + c16) * 32 + sq * 8;
  }

  // ---- prologue: stage tile0, prefetch A(1) into regs ----
  float4 ax = *(const float4*)(aG);
  float4 ay = *(const float4*)(aG + 4);
  stageA(buf0 + aWoff, ax, ay);
  ax = *(const float4*)(aG + 32);
  ay = *(const float4*)(aG + 36);
  __syncthreads();

  // ---- dbuf K loop: stage(kt+1) || B-direct + compute(kt) ----
#pragma unroll 2
  for (int kt = 0; kt < 15; ++kt) {
    unsigned char* const sb = (kt & 1) ? buf0 : buf1;
    unsigned char* const cb = (kt & 1) ? buf1 : buf0;
    stageA(sb + aWoff, ax, ay);
    if (kt < 14) {
      ax = *(const float4*)(aG + (kt + 2) * 32);
      ay = *(const float4*)(aG + (kt + 2) * 32 + 4);
    }
    computeT(cb, kt, bQ, wid, c16, slot, acc);
    __syncthreads();
  }
  computeT(buf1, 15, bQ, wid, c16, slot, acc);
  __syncthreads();

  // spill acc to Ctile (bf16)
#pragma unroll
  for (int r = 0; r < 4; ++r)
#pragma unroll
    for (int i = 0; i < 7; ++i) {
      const int f = wid + (i << 2);
      if (f < 25) {
        const int col = (f << 4) + c16;
        const int rowb = (r << 4) + (sq << 2);
#pragma unroll
        for (int j = 0; j < 4; ++j)
          Ctile[(rowb + j) * CSTRIDE + col] = f2bf(acc[r][i][j]);
      }
    }
  __syncthreads();

  // ---------------- epilogue: 4-lane group (stride-16 lanes) per row --------
  const int rloc = (wid << 4) + c16;  // 0..63
  const int b = b0 + rloc;
  const int qt = sq;
  const u16* crow = Ctile + rloc * CSTRIDE;
  const float* srow = states + (size_t)b * 512;

  float m[4][16];
#pragma unroll
  for (int h = 0; h < 4; ++h) {
    u32x4 w0 = *(const u32x4*)(crow + h * 64 + qt * 16);
    u32x4 w1 = *(const u32x4*)(crow + h * 64 + qt * 16 + 8);
#pragma unroll
    for (int k = 0; k < 4; ++k) {
      m[h][2 * k] = bfl(w0[k]);     m[h][2 * k + 1] = bfh(w0[k]);
      m[h][8 + 2 * k] = bfl(w1[k]); m[h][8 + 2 * k + 1] = bfh(w1[k]);
    }
  }

  float lp[4][8];
#pragma unroll
  for (int h = 0; h < 4; ++h)
#pragma unroll
    for (int a = 0; a < 8; ++a) lp[h][a] = 0.f;

#pragma unroll
  for (int a = 0; a < 8; ++a) {
    const float* xp = srow + a * 64 + qt * 16;
    float4 v0 = *(const float4*)(xp);
    float4 v1 = *(const float4*)(xp + 4);
    float4 v2 = *(const float4*)(xp + 8);
    float4 v3 = *(const float4*)(xp + 12);
    float xv[16] = {v0.x, v0.y, v0.z, v0.w, v1.x, v1.y, v1.z, v1.w,
                    v2.x, v2.y, v2.z, v2.w, v3.x, v3.y, v3.z, v3.w};
#pragma unroll
    for (int h = 0; h < 4; ++h) {
      float s = 0.f;
#pragma unroll
      for (int t2 = 0; t2 < 16; ++t2) s = fmaf(m[h][t2], xv[t2], s);
      lp[h][a] += s;
    }
  }
#pragma unroll
  for (int h = 0; h < 4; ++h)
#pragma unroll
    for (int a = 0; a < 8; ++a) {
      float v = lp[h][a];
      v += __shfl_xor(v, 16, 64);
      v += __shfl_xor(v, 32, 64);
      lp[h][a] = v;
    }
  // u=64 term (agent_qs)
  float4 q0 = *(const float4*)(agent_qs + (size_t)b * 8);
  float4 q1 = *(const float4*)(agent_qs + (size_t)b * 8 + 4);
  float qv[8] = {q0.x, q0.y, q0.z, q0.w, q1.x, q1.y, q1.z, q1.w};
  u32x2 w64 = *(const u32x2*)(crow + 256);
  float m64[4] = {bfl(w64[0]), bfh(w64[0]), bfl(w64[1]), bfh(w64[1])};
#pragma unroll
  for (int h = 0; h < 4; ++h)
#pragma unroll
    for (int a = 0; a < 8; ++a) lp[h][a] = fmaf(m64[h], qv[a], lp[h][a]);

  float magp = 0.f;
  if (qt == 0) {
#pragma unroll
    for (int h = 0; h < 4; ++h)
#pragma unroll
      for (int a = 0; a < 8; ++a) magp = fmaf(lp[h][a], lp[h][a], magp);
  }
  // v partial: 32 e per lane-quarter
  float bvv[32], wvv[32], cv[32];
#pragma unroll
  for (int g = 0; g < 8; ++g) {
    *(float4*)(bvv + g * 4) = *(const float4*)(bv1 + qt * 32 + g * 4);
    *(float4*)(wvv + g * 4) = *(const float4*)(Wv2 + qt * 32 + g * 4);
  }
#pragma unroll
  for (int g = 0; g < 4; ++g) {
    u32x4 wv = *(const u32x4*)(crow + 264 + qt * 32 + g * 8);
#pragma unroll
    for (int k = 0; k < 4; ++k) {
      cv[g * 8 + 2 * k] = bfl(wv[k]); cv[g * 8 + 2 * k + 1] = bfh(wv[k]);
    }
  }
  float vp = 0.f;
#pragma unroll
  for (int e2 = 0; e2 < 32; ++e2)
    vp = fmaf(fmaxf(cv[e2] + bvv[e2], 0.f), wvv[e2], vp);
  vp += __shfl_xor(vp, 16, 64);
  vp += __shfl_xor(vp, 32, 64);

  int av[8];
  const int* ap = actions + (size_t)b * 8;
#pragma unroll
  for (int a = 0; a < 8; ++a) av[a] = ap[a];

  u32x2 ww = *(const u32x2*)(crow + 392);
  float whr[4] = {bfl(ww[0]), bfh(ww[0]), bfl(ww[1]), bfh(ww[1])};
  float4 bh4 = *(const float4*)(bh);
  float bhv[4] = {bh4.x, bh4.y, bh4.z, bh4.w};

  const float scale = 0.088388347648318447f;  // 1/sqrt(128)
  float att[8];
#pragma unroll
  for (int a = 0; a < 8; ++a) att[a] = 0.f;
  float entp[4];
#pragma unroll
  for (int h = 0; h < 4; ++h) {
    float whv = fabsf(whr[h] + bhv[h]);
    float sc[8];
#pragma unroll
    for (int a = 0; a < 8; ++a)
      sc[a] = (av[a] == 0) ? NEGV : lp[h][a] * scale;
    float mx = sc[0];
#pragma unroll
    for (int a = 1; a < 8; ++a) mx = fmaxf(mx, sc[a]);
    float ex[8];
    float sum = 0.f;
#pragma unroll
    for (int a = 0; a < 8; ++a) { ex[a] = __expf(sc[a] - mx); sum += ex[a]; }
    float inv = 1.f / sum;
    float ent = 0.f;
#pragma unroll
    for (int a = 0; a < 8; ++a) {
      float w = ex[a] * inv;
      att[a] = fmaf(w, whv, att[a]);
      ent = fmaf(w, __logf(w + 1e-8f), ent);
    }
    entp[h] = ent;
  }

  if (qt == 0) {
    float4 o0 = {att[0], att[1], att[2], att[3]};
    float4 o1 = {att[4], att[5], att[6], att[7]};
    *(float4*)(out + (size_t)b * 8) = o0;
    *(float4*)(out + (size_t)b * 8 + 4) = o1;
    out[262144 + b] = vp + bv2[0];
  }

  float r0 = magp;
  float r1 = (qt == 0) ? entp[0] : 0.f;
  float r2 = (qt == 0) ? entp[1] : 0.f;
  float r3 = (qt == 0) ? entp[2] : 0.f;
  float r4 = (qt == 0) ? entp[3] : 0.f;
#pragma unroll
  for (int off = 1; off < 64; off <<= 1) {
    r0 += __shfl_xor(r0, off, 64);
    r1 += __shfl_xor(r1, off, 64);
    r2 += __shfl_xor(r2, off, 64);
    r3 += __shfl_xor(r3, off, 64);
    r4 += __shfl_xor(r4, off, 64);
  }
  if (lane == 0) {
    red[wid * 5 + 0] = r0; red[wid * 5 + 1] = r1; red[wid * 5 + 2] = r2;
    red[wid * 5 + 3] = r3; red[wid * 5 + 4] = r4;
  }
  __syncthreads();
  if (tid < 5) {
    float s = red[tid] + red[5 + tid] + red[10 + tid] + red[15 + tid];
    atomicAdd(&accs[tid], s);
  }
  __syncthreads();  // block's atomics retired before counting
  if (tid == 0) {
    u32* cnt = (u32*)(accs + 8);
    if (atomicAdd(cnt, 1u) == 511u) {  // last block finalizes
      float a0 = atomicAdd(&accs[0], 0.f);
      float a1 = atomicAdd(&accs[1], 0.f);
      float a2 = atomicAdd(&accs[2], 0.f);
      float a3 = atomicAdd(&accs[3], 0.f);
      float a4 = atomicAdd(&accs[4], 0.f);
      out[294912] = 0.001f * a0 * (1.0f / 262144.0f);
      out[294913] = -a1 * (1.0f / 32768.0f);
      out[294914] = -a2 * (1.0f / 32768.0f);
      out[294915] = -a3 * (1.0f / 32768.0f);
      out[294916] = -a4 * (1.0f / 32768.0f);
    }
  }
}

extern "C" void kernel_launch(void* const* d_in, const int* in_sizes, int n_in,
                              void* d_out, int out_size, void* d_ws, size_t ws_size,
                              hipStream_t stream) {
  const float* agent_qs = (const float*)d_in[0];
  const float* states   = (const float*)d_in[1];
  const int*   actions  = (const int*)d_in[2];
  const float* Wsel = (const float*)d_in[3];
  const float* Wkey = (const float*)d_in[4];
  const float* Wv1  = (const float*)d_in[5];
  const float* bv1  = (const float*)d_in[6];
  const float* Wv2  = (const float*)d_in[7];
  const float* bv2  = (const float*)d_in[8];
  const float* Wh   = (const float*)d_in[9];
  const float* bh   = (const float*)d_in[10];
  float* out = (float*)d_out;
  float* accs = (float*)d_ws;                    // 16 floats (incl. counter)
  u16* Wp = (u16*)((char*)d_ws + 64);            // 16 tiles x 400 x 32 bf16

  hipLaunchKernelGGL(kprep, dim3(136), dim3(256), 0, stream,
                     Wsel, Wkey, Wv1, Wh, Wp, accs);
  hipLaunchKernelGGL(kmain, dim3(512), dim3(256), 0, stream,
                     states, agent_qs, actions, Wp, bv1, Wv2, bv2, bh, out, accs);
}

// Round 8
// 64.591 us; speedup vs baseline: 2.2093x; 1.6982x over previous
//
#include <hip/hip_runtime.h>

// Qatten forward:
//   M[h,u,s] = sum_e W_key[h,e,u]*W_sel[h,e,s]        (kprep, LDS-tiled)
//   panel row p (400 rows, bf16, K-tile-blocked in Wp[kt][p][32]):
//     p = h*64+u (u<64): M[h,u,:];  256+h: M[h,64,:];  264+e: Wv1[e,:];
//     392+h: Wh[h,:];  260-263,396-399: zero
//   kmain (256 thr, 4 waves, 2 blocks/CU): C = states x panel^T, 16x16x32
//     bf16 MFMA intrinsic. FULL A-tile (64x512 bf16 = 64KB, 16 R3-format
//     sub-tiles) staged in LDS up front -> K-loop has ZERO barriers:
//     per kt: 4 ds_read_b128 (A) + 7 coalesced 16B global loads (B, L2) +
//     28 MFMA, fully unrolled, latency hidden by ILP + 2 waves/SIMD.
//     launch_bounds(256,2): 256-reg cap, acc[4][7] stays in registers.

typedef unsigned short u16;
typedef unsigned int u32;
typedef float f32x4 __attribute__((ext_vector_type(4)));
typedef short s16x8 __attribute__((ext_vector_type(8)));
typedef unsigned int u32x4 __attribute__((ext_vector_type(4)));
typedef unsigned int u32x2 __attribute__((ext_vector_type(2)));

#define NEGV -99999999.0f
#define CSTRIDE 424   // u16; 212 words = 20 mod 32 -> adjacent rows offset banks

__device__ __forceinline__ u16 f2bf(float f) {
  union { float f; u32 u; } v; v.f = f;
  u32 r = v.u + 0x7fffu + ((v.u >> 16) & 1u);
  return (u16)(r >> 16);
}
__device__ __forceinline__ float bfl(u32 w) { union { u32 u; float f; } v; v.u = w << 16; return v.f; }
__device__ __forceinline__ float bfh(u32 w) { union { u32 u; float f; } v; v.u = w & 0xffff0000u; return v.f; }

// panel element (row p, col s) -> Wp[kt][p][s&31], plain layout
__device__ __forceinline__ void panel_store(u16* Wp, int p, int s, float v) {
  Wp[(s >> 5) * 12800 + p * 32 + (s & 31)] = f2bf(v);
}

// ---------------- kprep ------------------------------------------------------
__global__ __launch_bounds__(256) void kprep(
    const float* __restrict__ Wsel, const float* __restrict__ Wkey,
    const float* __restrict__ Wv1, const float* __restrict__ Wh,
    u16* __restrict__ Wp, float* __restrict__ accs) {
  const int bid = blockIdx.x, t = threadIdx.x;
  if (bid < 128) {
    __shared__ float wsS[2048];   // [e][16]
    __shared__ float wkS[8320];   // [e][65]
    const int h = bid >> 5, s0 = (bid & 31) << 4;
    for (int i = t; i < 2048; i += 256)
      wsS[i] = Wsel[((size_t)h * 128 + (i >> 4)) * 512 + s0 + (i & 15)];
    for (int i = t; i < 8320; i += 256)
      wkS[i] = Wkey[(size_t)h * 8320 + i];
    __syncthreads();
    {
      const int u = t >> 2, sl0 = (t & 3) << 2;
      float a0 = 0.f, a1 = 0.f, a2 = 0.f, a3 = 0.f;
      for (int e = 0; e < 128; ++e) {
        const float k = wkS[e * 65 + u];
        const float* wr = wsS + e * 16 + sl0;
        a0 = fmaf(k, wr[0], a0); a1 = fmaf(k, wr[1], a1);
        a2 = fmaf(k, wr[2], a2); a3 = fmaf(k, wr[3], a3);
      }
      const int p = h * 64 + u, s = s0 + sl0;
      panel_store(Wp, p, s, a0);     panel_store(Wp, p, s + 1, a1);
      panel_store(Wp, p, s + 2, a2); panel_store(Wp, p, s + 3, a3);
    }
    if (t < 16) {  // u = 64 row
      float a = 0.f;
      for (int e = 0; e < 128; ++e)
        a = fmaf(wkS[e * 65 + 64], wsS[e * 16 + t], a);
      panel_store(Wp, 256 + h, s0 + t, a);
    }
  } else {
    if (bid == 128 && t < 16) accs[t] = 0.f;
    for (int row = 260 + (bid - 128); row < 400; row += 8) {
      for (int s = t; s < 512; s += 256) {
        float v = 0.f;
        if (row >= 264 && row < 392) v = Wv1[(row - 264) * 512 + s];
        else if (row >= 392 && row < 396) v = Wh[(row - 392) * 512 + s];
        panel_store(Wp, row, s, v);
      }
    }
  }
}

// ---------------- kmain ------------------------------------------------------
__device__ __forceinline__ void stageA(unsigned char* dst, const float4& x0, const float4& x1) {
  u32x4 aw;
  aw[0] = (u32)f2bf(x0.x) | ((u32)f2bf(x0.y) << 16);
  aw[1] = (u32)f2bf(x0.z) | ((u32)f2bf(x0.w) << 16);
  aw[2] = (u32)f2bf(x1.x) | ((u32)f2bf(x1.y) << 16);
  aw[3] = (u32)f2bf(x1.z) | ((u32)f2bf(x1.w) << 16);
  *(u32x4*)dst = aw;
}

__global__ __launch_bounds__(256, 2) void kmain(
    const float* __restrict__ states, const float* __restrict__ agent_qs,
    const int* __restrict__ actions, const u16* __restrict__ Wp,
    const float* __restrict__ bv1, const float* __restrict__ Wv2,
    const float* __restrict__ bv2, const float* __restrict__ bh,
    float* __restrict__ out, float* __restrict__ accs) {
  // LDS: Afull = 16 sub-tiles x [64 rows][64B] = 65536B.
  // Ctile [64][CSTRIDE] u16 (54272B) reuses the same space after a barrier.
  // red (80B) at 65536. High-water 65616B -> 2 blocks/CU.
  __shared__ __align__(16) unsigned char smem[65536 + 80];
  u16* const Ctile = (u16*)smem;
  float* const red = (float*)(smem + 65536);

  const int tid = threadIdx.x;
  const int wid = tid >> 6;
  const int lane = tid & 63;
  const int c16 = lane & 15, sq = lane >> 4;
  const int slot = sq ^ ((c16 >> 1) & 3);
  const int b0 = blockIdx.x * 64;

  const f32x4 zf = {0.f, 0.f, 0.f, 0.f};
  f32x4 acc[4][7];
#pragma unroll
  for (int r = 0; r < 4; ++r)
#pragma unroll
    for (int i = 0; i < 7; ++i) acc[r][i] = zf;

  // ---- stage the WHOLE A tile (16 sub-tiles), then one barrier ----
  const int ar = tid >> 2, ac = tid & 3;
  const float* aG = states + (size_t)(b0 + ar) * 512 + ac * 8;
  const int aWoff = ar * 64 + ((ac ^ ((ar >> 1) & 3)) << 4);
#pragma unroll
  for (int kt = 0; kt < 16; ++kt) {
    float4 x0 = *(const float4*)(aG + kt * 32);
    float4 x1 = *(const float4*)(aG + kt * 32 + 4);
    stageA(smem + kt * 4096 + aWoff, x0, x1);
  }
  __syncthreads();

  // B: colfrag f = wid + 4i; lane reads Wp[kt][f*16+c16][sq*8..+8] (1KB/wave)
  const u16* bQ[7];
#pragma unroll
  for (int i = 0; i < 7; ++i) {
    const int f = wid + (i << 2);
    bQ[i] = Wp + ((f < 25 ? f : 0) * 16 + c16) * 32 + sq * 8;
  }

  // ---- barrier-free K loop ----
#pragma unroll
  for (int kt = 0; kt < 16; ++kt) {
    s16x8 bfr[7];
#pragma unroll
    for (int i = 0; i < 7; ++i)
      if (wid + (i << 2) < 25)
        bfr[i] = *(const s16x8*)(bQ[i] + kt * 12800);
    s16x8 af[4];
#pragma unroll
    for (int r = 0; r < 4; ++r)
      af[r] = *(const s16x8*)(smem + kt * 4096 + (r * 16 + c16) * 64 + slot * 16);
#pragma unroll
    for (int i = 0; i < 7; ++i)
      if (wid + (i << 2) < 25) {
#pragma unroll
        for (int r = 0; r < 4; ++r)
          acc[r][i] = __builtin_amdgcn_mfma_f32_16x16x32_bf16(
              af[r], bfr[i], acc[r][i], 0, 0, 0);
      }
  }
  __syncthreads();  // A-tile dead; Ctile may overwrite

  // spill acc to Ctile (bf16)
#pragma unroll
  for (int r = 0; r < 4; ++r)
#pragma unroll
    for (int i = 0; i < 7; ++i) {
      const int f = wid + (i << 2);
      if (f < 25) {
        const int col = (f << 4) + c16;
        const int rowb = (r << 4) + (sq << 2);
#pragma unroll
        for (int j = 0; j < 4; ++j)
          Ctile[(rowb + j) * CSTRIDE + col] = f2bf(acc[r][i][j]);
      }
    }
  __syncthreads();

  // ---------------- epilogue: 4-lane group (stride-16 lanes) per row --------
  const int rloc = (wid << 4) + c16;  // 0..63
  const int b = b0 + rloc;
  const int qt = sq;
  const u16* crow = Ctile + rloc * CSTRIDE;
  const float* srow = states + (size_t)b * 512;

  float m[4][16];
#pragma unroll
  for (int h = 0; h < 4; ++h) {
    u32x4 w0 = *(const u32x4*)(crow + h * 64 + qt * 16);
    u32x4 w1 = *(const u32x4*)(crow + h * 64 + qt * 16 + 8);
#pragma unroll
    for (int k = 0; k < 4; ++k) {
      m[h][2 * k] = bfl(w0[k]);     m[h][2 * k + 1] = bfh(w0[k]);
      m[h][8 + 2 * k] = bfl(w1[k]); m[h][8 + 2 * k + 1] = bfh(w1[k]);
    }
  }

  float lp[4][8];
#pragma unroll
  for (int h = 0; h < 4; ++h)
#pragma unroll
    for (int a = 0; a < 8; ++a) lp[h][a] = 0.f;

#pragma unroll
  for (int a = 0; a < 8; ++a) {
    const float* xp = srow + a * 64 + qt * 16;
    float4 v0 = *(const float4*)(xp);
    float4 v1 = *(const float4*)(xp + 4);
    float4 v2 = *(const float4*)(xp + 8);
    float4 v3 = *(const float4*)(xp + 12);
    float xv[16] = {v0.x, v0.y, v0.z, v0.w, v1.x, v1.y, v1.z, v1.w,
                    v2.x, v2.y, v2.z, v2.w, v3.x, v3.y, v3.z, v3.w};
#pragma unroll
    for (int h = 0; h < 4; ++h) {
      float s = 0.f;
#pragma unroll
      for (int t2 = 0; t2 < 16; ++t2) s = fmaf(m[h][t2], xv[t2], s);
      lp[h][a] += s;
    }
  }
#pragma unroll
  for (int h = 0; h < 4; ++h)
#pragma unroll
    for (int a = 0; a < 8; ++a) {
      float v = lp[h][a];
      v += __shfl_xor(v, 16, 64);
      v += __shfl_xor(v, 32, 64);
      lp[h][a] = v;
    }
  // u=64 term (agent_qs)
  float4 q0 = *(const float4*)(agent_qs + (size_t)b * 8);
  float4 q1 = *(const float4*)(agent_qs + (size_t)b * 8 + 4);
  float qv[8] = {q0.x, q0.y, q0.z, q0.w, q1.x, q1.y, q1.z, q1.w};
  u32x2 w64 = *(const u32x2*)(crow + 256);
  float m64[4] = {bfl(w64[0]), bfh(w64[0]), bfl(w64[1]), bfh(w64[1])};
#pragma unroll
  for (int h = 0; h < 4; ++h)
#pragma unroll
    for (int a = 0; a < 8; ++a) lp[h][a] = fmaf(m64[h], qv[a], lp[h][a]);

  float magp = 0.f;
  if (qt == 0) {
#pragma unroll
    for (int h = 0; h < 4; ++h)
#pragma unroll
      for (int a = 0; a < 8; ++a) magp = fmaf(lp[h][a], lp[h][a], magp);
  }
  // v partial: 32 e per lane-quarter
  float bvv[32], wvv[32], cv[32];
#pragma unroll
  for (int g = 0; g < 8; ++g) {
    *(float4*)(bvv + g * 4) = *(const float4*)(bv1 + qt * 32 + g * 4);
    *(float4*)(wvv + g * 4) = *(const float4*)(Wv2 + qt * 32 + g * 4);
  }
#pragma unroll
  for (int g = 0; g < 4; ++g) {
    u32x4 wv = *(const u32x4*)(crow + 264 + qt * 32 + g * 8);
#pragma unroll
    for (int k = 0; k < 4; ++k) {
      cv[g * 8 + 2 * k] = bfl(wv[k]); cv[g * 8 + 2 * k + 1] = bfh(wv[k]);
    }
  }
  float vp = 0.f;
#pragma unroll
  for (int e2 = 0; e2 < 32; ++e2)
    vp = fmaf(fmaxf(cv[e2] + bvv[e2], 0.f), wvv[e2], vp);
  vp += __shfl_xor(vp, 16, 64);
  vp += __shfl_xor(vp, 32, 64);

  int av[8];
  const int* ap = actions + (size_t)b * 8;
#pragma unroll
  for (int a = 0; a < 8; ++a) av[a] = ap[a];

  u32x2 ww = *(const u32x2*)(crow + 392);
  float whr[4] = {bfl(ww[0]), bfh(ww[0]), bfl(ww[1]), bfh(ww[1])};
  float4 bh4 = *(const float4*)(bh);
  float bhv[4] = {bh4.x, bh4.y, bh4.z, bh4.w};

  const float scale = 0.088388347648318447f;  // 1/sqrt(128)
  float att[8];
#pragma unroll
  for (int a = 0; a < 8; ++a) att[a] = 0.f;
  float entp[4];
#pragma unroll
  for (int h = 0; h < 4; ++h) {
    float whv = fabsf(whr[h] + bhv[h]);
    float sc[8];
#pragma unroll
    for (int a = 0; a < 8; ++a)
      sc[a] = (av[a] == 0) ? NEGV : lp[h][a] * scale;
    float mx = sc[0];
#pragma unroll
    for (int a = 1; a < 8; ++a) mx = fmaxf(mx, sc[a]);
    float ex[8];
    float sum = 0.f;
#pragma unroll
    for (int a = 0; a < 8; ++a) { ex[a] = __expf(sc[a] - mx); sum += ex[a]; }
    float inv = 1.f / sum;
    float ent = 0.f;
#pragma unroll
    for (int a = 0; a < 8; ++a) {
      float w = ex[a] * inv;
      att[a] = fmaf(w, whv, att[a]);
      ent = fmaf(w, __logf(w + 1e-8f), ent);
    }
    entp[h] = ent;
  }

  if (qt == 0) {
    float4 o0 = {att[0], att[1], att[2], att[3]};
    float4 o1 = {att[4], att[5], att[6], att[7]};
    *(float4*)(out + (size_t)b * 8) = o0;
    *(float4*)(out + (size_t)b * 8 + 4) = o1;
    out[262144 + b] = vp + bv2[0];
  }

  float r0 = magp;
  float r1 = (qt == 0) ? entp[0] : 0.f;
  float r2 = (qt == 0) ? entp[1] : 0.f;
  float r3 = (qt == 0) ? entp[2] : 0.f;
  float r4 = (qt == 0) ? entp[3] : 0.f;
#pragma unroll
  for (int off = 1; off < 64; off <<= 1) {
    r0 += __shfl_xor(r0, off, 64);
    r1 += __shfl_xor(r1, off, 64);
    r2 += __shfl_xor(r2, off, 64);
    r3 += __shfl_xor(r3, off, 64);
    r4 += __shfl_xor(r4, off, 64);
  }
  if (lane == 0) {
    red[wid * 5 + 0] = r0; red[wid * 5 + 1] = r1; red[wid * 5 + 2] = r2;
    red[wid * 5 + 3] = r3; red[wid * 5 + 4] = r4;
  }
  __syncthreads();
  if (tid < 5) {
    float s = red[tid] + red[5 + tid] + red[10 + tid] + red[15 + tid];
    atomicAdd(&accs[tid], s);
  }
  __syncthreads();  // block's atomics retired before counting
  if (tid == 0) {
    u32* cnt = (u32*)(accs + 8);
    if (atomicAdd(cnt, 1u) == 511u) {  // last block finalizes
      float a0 = atomicAdd(&accs[0], 0.f);
      float a1 = atomicAdd(&accs[1], 0.f);
      float a2 = atomicAdd(&accs[2], 0.f);
      float a3 = atomicAdd(&accs[3], 0.f);
      float a4 = atomicAdd(&accs[4], 0.f);
      out[294912] = 0.001f * a0 * (1.0f / 262144.0f);
      out[294913] = -a1 * (1.0f / 32768.0f);
      out[294914] = -a2 * (1.0f / 32768.0f);
      out[294915] = -a3 * (1.0f / 32768.0f);
      out[294916] = -a4 * (1.0f / 32768.0f);
    }
  }
}

extern "C" void kernel_launch(void* const* d_in, const int* in_sizes, int n_in,
                              void* d_out, int out_size, void* d_ws, size_t ws_size,
                              hipStream_t stream) {
  const float* agent_qs = (const float*)d_in[0];
  const float* states   = (const float*)d_in[1];
  const int*   actions  = (const int*)d_in[2];
  const float* Wsel = (const float*)d_in[3];
  const float* Wkey = (const float*)d_in[4];
  const float* Wv1  = (const float*)d_in[5];
  const float* bv1  = (const float*)d_in[6];
  const float* Wv2  = (const float*)d_in[7];
  const float* bv2  = (const float*)d_in[8];
  const float* Wh   = (const float*)d_in[9];
  const float* bh   = (const float*)d_in[10];
  float* out = (float*)d_out;
  float* accs = (float*)d_ws;                    // 16 floats (incl. counter)
  u16* Wp = (u16*)((char*)d_ws + 64);            // 16 tiles x 400 x 32 bf16

  hipLaunchKernelGGL(kprep, dim3(136), dim3(256), 0, stream,
                     Wsel, Wkey, Wv1, Wh, Wp, accs);
  hipLaunchKernelGGL(kmain, dim3(512), dim3(256), 0, stream,
                     states, agent_qs, actions, Wp, bv1, Wv2, bv2, bh, out, accs);
}

// Round 9
// 60.527 us; speedup vs baseline: 2.3576x; 1.0671x over previous
//
#include <hip/hip_runtime.h>

// Qatten forward:
//   M[h,u,s] = sum_e W_key[h,e,u]*W_sel[h,e,s]        (kprep, LDS-tiled)
//   panel row p (400 rows, bf16, K-tile-blocked in Wp[kt][p][32]):
//     p = h*64+u (u<64): M[h,u,:];  256+h: M[h,64,:];  264+e: Wv1[e,:];
//     392+h: Wh[h,:];  260-263,396-399: zero
//   kmain (256 thr, 4 waves, 2 blocks/CU): C = states x panel^T, 16x16x32
//     bf16 MFMA intrinsic. FULL A-tile staged with 32 loads IN FLIGHT
//     (tmp[32] static array -> Little's-law HBM saturation), barrier-free
//     K-loop (B direct from L2 panel), epilogue x read from the LDS A-tile
//     (bf16) before the Ctile spill overwrites it.

typedef unsigned short u16;
typedef unsigned int u32;
typedef float f32x4 __attribute__((ext_vector_type(4)));
typedef short s16x8 __attribute__((ext_vector_type(8)));
typedef unsigned int u32x4 __attribute__((ext_vector_type(4)));
typedef unsigned int u32x2 __attribute__((ext_vector_type(2)));

#define NEGV -99999999.0f
#define CSTRIDE 424   // u16; 212 words = 20 mod 32 -> adjacent rows offset banks

__device__ __forceinline__ u16 f2bf(float f) {
  union { float f; u32 u; } v; v.f = f;
  u32 r = v.u + 0x7fffu + ((v.u >> 16) & 1u);
  return (u16)(r >> 16);
}
__device__ __forceinline__ float bfl(u32 w) { union { u32 u; float f; } v; v.u = w << 16; return v.f; }
__device__ __forceinline__ float bfh(u32 w) { union { u32 u; float f; } v; v.u = w & 0xffff0000u; return v.f; }

// panel element (row p, col s) -> Wp[kt][p][s&31], plain layout
__device__ __forceinline__ void panel_store(u16* Wp, int p, int s, float v) {
  Wp[(s >> 5) * 12800 + p * 32 + (s & 31)] = f2bf(v);
}

// ---------------- kprep ------------------------------------------------------
__global__ __launch_bounds__(256) void kprep(
    const float* __restrict__ Wsel, const float* __restrict__ Wkey,
    const float* __restrict__ Wv1, const float* __restrict__ Wh,
    u16* __restrict__ Wp, float* __restrict__ accs) {
  const int bid = blockIdx.x, t = threadIdx.x;
  if (bid < 128) {
    __shared__ float wsS[2048];   // [e][16]
    __shared__ float wkS[8320];   // [e][65]
    const int h = bid >> 5, s0 = (bid & 31) << 4;
    for (int i = t; i < 2048; i += 256)
      wsS[i] = Wsel[((size_t)h * 128 + (i >> 4)) * 512 + s0 + (i & 15)];
    for (int i = t; i < 8320; i += 256)
      wkS[i] = Wkey[(size_t)h * 8320 + i];
    __syncthreads();
    {
      const int u = t >> 2, sl0 = (t & 3) << 2;
      float a0 = 0.f, a1 = 0.f, a2 = 0.f, a3 = 0.f;
      for (int e = 0; e < 128; ++e) {
        const float k = wkS[e * 65 + u];
        const float* wr = wsS + e * 16 + sl0;
        a0 = fmaf(k, wr[0], a0); a1 = fmaf(k, wr[1], a1);
        a2 = fmaf(k, wr[2], a2); a3 = fmaf(k, wr[3], a3);
      }
      const int p = h * 64 + u, s = s0 + sl0;
      panel_store(Wp, p, s, a0);     panel_store(Wp, p, s + 1, a1);
      panel_store(Wp, p, s + 2, a2); panel_store(Wp, p, s + 3, a3);
    }
    if (t < 16) {  // u = 64 row
      float a = 0.f;
      for (int e = 0; e < 128; ++e)
        a = fmaf(wkS[e * 65 + 64], wsS[e * 16 + t], a);
      panel_store(Wp, 256 + h, s0 + t, a);
    }
  } else {
    if (bid == 128 && t < 16) accs[t] = 0.f;
    for (int row = 260 + (bid - 128); row < 400; row += 8) {
      for (int s = t; s < 512; s += 256) {
        float v = 0.f;
        if (row >= 264 && row < 392) v = Wv1[(row - 264) * 512 + s];
        else if (row >= 392 && row < 396) v = Wh[(row - 392) * 512 + s];
        panel_store(Wp, row, s, v);
      }
    }
  }
}

// ---------------- kmain ------------------------------------------------------
__global__ __launch_bounds__(256, 2) void kmain(
    const float* __restrict__ states, const float* __restrict__ agent_qs,
    const int* __restrict__ actions, const u16* __restrict__ Wp,
    const float* __restrict__ bv1, const float* __restrict__ Wv2,
    const float* __restrict__ bv2, const float* __restrict__ bh,
    float* __restrict__ out, float* __restrict__ accs) {
  // LDS: Afull = 16 sub-tiles x [64 rows][64B] = 65536B.
  // Ctile [64][CSTRIDE] u16 (54272B) reuses the same space after the x-read.
  // red (80B) at 65536. High-water 65616B -> 2 blocks/CU.
  __shared__ __align__(16) unsigned char smem[65536 + 80];
  u16* const Ctile = (u16*)smem;
  float* const red = (float*)(smem + 65536);

  const int tid = threadIdx.x;
  const int wid = tid >> 6;
  const int lane = tid & 63;
  const int c16 = lane & 15, sq = lane >> 4;
  const int slot = sq ^ ((c16 >> 1) & 3);
  const int b0 = blockIdx.x * 64;

  // ---- stage the WHOLE A tile: 32 independent loads in flight ----
  const int ar = tid >> 2, ac = tid & 3;
  const float* aG = states + (size_t)(b0 + ar) * 512 + ac * 8;
  const int aWoff = ar * 64 + ((ac ^ ((ar >> 1) & 3)) << 4);
  {
    float4 tmp[32];
#pragma unroll
    for (int i = 0; i < 32; ++i)
      tmp[i] = *(const float4*)(aG + (i >> 1) * 32 + (i & 1) * 4);
#pragma unroll
    for (int k = 0; k < 16; ++k) {
      u32x4 aw;
      aw[0] = (u32)f2bf(tmp[2 * k].x) | ((u32)f2bf(tmp[2 * k].y) << 16);
      aw[1] = (u32)f2bf(tmp[2 * k].z) | ((u32)f2bf(tmp[2 * k].w) << 16);
      aw[2] = (u32)f2bf(tmp[2 * k + 1].x) | ((u32)f2bf(tmp[2 * k + 1].y) << 16);
      aw[3] = (u32)f2bf(tmp[2 * k + 1].z) | ((u32)f2bf(tmp[2 * k + 1].w) << 16);
      *(u32x4*)(smem + k * 4096 + aWoff) = aw;
    }
  }
  __syncthreads();

  const f32x4 zf = {0.f, 0.f, 0.f, 0.f};
  f32x4 acc[4][7];
#pragma unroll
  for (int r = 0; r < 4; ++r)
#pragma unroll
    for (int i = 0; i < 7; ++i) acc[r][i] = zf;

  // B: colfrag f = wid + 4i; lane reads Wp[kt][f*16+c16][sq*8..+8] (1KB/wave)
  const u16* bQ[7];
#pragma unroll
  for (int i = 0; i < 7; ++i) {
    const int f = wid + (i << 2);
    bQ[i] = Wp + ((f < 25 ? f : 0) * 16 + c16) * 32 + sq * 8;
  }

  // ---- barrier-free K loop ----
#pragma unroll
  for (int kt = 0; kt < 16; ++kt) {
    s16x8 bfr[7];
#pragma unroll
    for (int i = 0; i < 7; ++i)
      if (wid + (i << 2) < 25)
        bfr[i] = *(const s16x8*)(bQ[i] + kt * 12800);
    s16x8 af[4];
#pragma unroll
    for (int r = 0; r < 4; ++r)
      af[r] = *(const s16x8*)(smem + kt * 4096 + (r * 16 + c16) * 64 + slot * 16);
#pragma unroll
    for (int i = 0; i < 7; ++i)
      if (wid + (i << 2) < 25) {
#pragma unroll
        for (int r = 0; r < 4; ++r)
          acc[r][i] = __builtin_amdgcn_mfma_f32_16x16x32_bf16(
              af[r], bfr[i], acc[r][i], 0, 0, 0);
      }
  }

  // ---- read epilogue x from the LDS A-tile (bf16) BEFORE Ctile overwrites --
  // lane (rloc, qt) agent a needs col = a*64 + qt*16 + jj (jj 0..15):
  //   subtile kt2 = 2a + (qt>>1); chunks ac0 = (qt&1)*2 and ac0+1 (swizzled)
  const int rloc = (wid << 4) + c16;  // 0..63
  const int qt = sq;
  u32x4 xw[16];
  {
    const int rsw = (rloc >> 1) & 3;
    const int ac0 = (qt & 1) << 1;
#pragma unroll
    for (int a = 0; a < 8; ++a) {
      const int base = (2 * a + (qt >> 1)) * 4096 + rloc * 64;
      xw[2 * a]     = *(const u32x4*)(smem + base + ((ac0 ^ rsw) << 4));
      xw[2 * a + 1] = *(const u32x4*)(smem + base + (((ac0 + 1) ^ rsw) << 4));
    }
  }
  __syncthreads();  // all x-reads done; A-tile may be overwritten

  // spill acc to Ctile (bf16)
#pragma unroll
  for (int r = 0; r < 4; ++r)
#pragma unroll
    for (int i = 0; i < 7; ++i) {
      const int f = wid + (i << 2);
      if (f < 25) {
        const int col = (f << 4) + c16;
        const int rowb = (r << 4) + (sq << 2);
#pragma unroll
        for (int j = 0; j < 4; ++j)
          Ctile[(rowb + j) * CSTRIDE + col] = f2bf(acc[r][i][j]);
      }
    }
  __syncthreads();

  // ---------------- epilogue: 4-lane group (stride-16 lanes) per row --------
  const int b = b0 + rloc;
  const u16* crow = Ctile + rloc * CSTRIDE;

  float m[4][16];
#pragma unroll
  for (int h = 0; h < 4; ++h) {
    u32x4 w0 = *(const u32x4*)(crow + h * 64 + qt * 16);
    u32x4 w1 = *(const u32x4*)(crow + h * 64 + qt * 16 + 8);
#pragma unroll
    for (int k = 0; k < 4; ++k) {
      m[h][2 * k] = bfl(w0[k]);     m[h][2 * k + 1] = bfh(w0[k]);
      m[h][8 + 2 * k] = bfl(w1[k]); m[h][8 + 2 * k + 1] = bfh(w1[k]);
    }
  }

  float lp[4][8];
#pragma unroll
  for (int h = 0; h < 4; ++h)
#pragma unroll
    for (int a = 0; a < 8; ++a) lp[h][a] = 0.f;

#pragma unroll
  for (int a = 0; a < 8; ++a) {
    float xv[16];
#pragma unroll
    for (int k = 0; k < 4; ++k) {
      xv[2 * k] = bfl(xw[2 * a][k]);         xv[2 * k + 1] = bfh(xw[2 * a][k]);
      xv[8 + 2 * k] = bfl(xw[2 * a + 1][k]); xv[8 + 2 * k + 1] = bfh(xw[2 * a + 1][k]);
    }
#pragma unroll
    for (int h = 0; h < 4; ++h) {
      float s = 0.f;
#pragma unroll
      for (int t2 = 0; t2 < 16; ++t2) s = fmaf(m[h][t2], xv[t2], s);
      lp[h][a] += s;
    }
  }
#pragma unroll
  for (int h = 0; h < 4; ++h)
#pragma unroll
    for (int a = 0; a < 8; ++a) {
      float v = lp[h][a];
      v += __shfl_xor(v, 16, 64);
      v += __shfl_xor(v, 32, 64);
      lp[h][a] = v;
    }
  // u=64 term (agent_qs)
  float4 q0 = *(const float4*)(agent_qs + (size_t)b * 8);
  float4 q1 = *(const float4*)(agent_qs + (size_t)b * 8 + 4);
  float qv[8] = {q0.x, q0.y, q0.z, q0.w, q1.x, q1.y, q1.z, q1.w};
  u32x2 w64 = *(const u32x2*)(crow + 256);
  float m64[4] = {bfl(w64[0]), bfh(w64[0]), bfl(w64[1]), bfh(w64[1])};
#pragma unroll
  for (int h = 0; h < 4; ++h)
#pragma unroll
    for (int a = 0; a < 8; ++a) lp[h][a] = fmaf(m64[h], qv[a], lp[h][a]);

  float magp = 0.f;
  if (qt == 0) {
#pragma unroll
    for (int h = 0; h < 4; ++h)
#pragma unroll
      for (int a = 0; a < 8; ++a) magp = fmaf(lp[h][a], lp[h][a], magp);
  }
  // v partial: 32 e per lane-quarter
  float bvv[32], wvv[32], cv[32];
#pragma unroll
  for (int g = 0; g < 8; ++g) {
    *(float4*)(bvv + g * 4) = *(const float4*)(bv1 + qt * 32 + g * 4);
    *(float4*)(wvv + g * 4) = *(const float4*)(Wv2 + qt * 32 + g * 4);
  }
#pragma unroll
  for (int g = 0; g < 4; ++g) {
    u32x4 wv = *(const u32x4*)(crow + 264 + qt * 32 + g * 8);
#pragma unroll
    for (int k = 0; k < 4; ++k) {
      cv[g * 8 + 2 * k] = bfl(wv[k]); cv[g * 8 + 2 * k + 1] = bfh(wv[k]);
    }
  }
  float vp = 0.f;
#pragma unroll
  for (int e2 = 0; e2 < 32; ++e2)
    vp = fmaf(fmaxf(cv[e2] + bvv[e2], 0.f), wvv[e2], vp);
  vp += __shfl_xor(vp, 16, 64);
  vp += __shfl_xor(vp, 32, 64);

  int av[8];
  const int* ap = actions + (size_t)b * 8;
#pragma unroll
  for (int a = 0; a < 8; ++a) av[a] = ap[a];

  u32x2 ww = *(const u32x2*)(crow + 392);
  float whr[4] = {bfl(ww[0]), bfh(ww[0]), bfl(ww[1]), bfh(ww[1])};
  float4 bh4 = *(const float4*)(bh);
  float bhv[4] = {bh4.x, bh4.y, bh4.z, bh4.w};

  const float scale = 0.088388347648318447f;  // 1/sqrt(128)
  float att[8];
#pragma unroll
  for (int a = 0; a < 8; ++a) att[a] = 0.f;
  float entp[4];
#pragma unroll
  for (int h = 0; h < 4; ++h) {
    float whv = fabsf(whr[h] + bhv[h]);
    float sc[8];
#pragma unroll
    for (int a = 0; a < 8; ++a)
      sc[a] = (av[a] == 0) ? NEGV : lp[h][a] * scale;
    float mx = sc[0];
#pragma unroll
    for (int a = 1; a < 8; ++a) mx = fmaxf(mx, sc[a]);
    float ex[8];
    float sum = 0.f;
#pragma unroll
    for (int a = 0; a < 8; ++a) { ex[a] = __expf(sc[a] - mx); sum += ex[a]; }
    float inv = 1.f / sum;
    float ent = 0.f;
#pragma unroll
    for (int a = 0; a < 8; ++a) {
      float w = ex[a] * inv;
      att[a] = fmaf(w, whv, att[a]);
      ent = fmaf(w, __logf(w + 1e-8f), ent);
    }
    entp[h] = ent;
  }

  if (qt == 0) {
    float4 o0 = {att[0], att[1], att[2], att[3]};
    float4 o1 = {att[4], att[5], att[6], att[7]};
    *(float4*)(out + (size_t)b * 8) = o0;
    *(float4*)(out + (size_t)b * 8 + 4) = o1;
    out[262144 + b] = vp + bv2[0];
  }

  float r0 = magp;
  float r1 = (qt == 0) ? entp[0] : 0.f;
  float r2 = (qt == 0) ? entp[1] : 0.f;
  float r3 = (qt == 0) ? entp[2] : 0.f;
  float r4 = (qt == 0) ? entp[3] : 0.f;
#pragma unroll
  for (int off = 1; off < 64; off <<= 1) {
    r0 += __shfl_xor(r0, off, 64);
    r1 += __shfl_xor(r1, off, 64);
    r2 += __shfl_xor(r2, off, 64);
    r3 += __shfl_xor(r3, off, 64);
    r4 += __shfl_xor(r4, off, 64);
  }
  if (lane == 0) {
    red[wid * 5 + 0] = r0; red[wid * 5 + 1] = r1; red[wid * 5 + 2] = r2;
    red[wid * 5 + 3] = r3; red[wid * 5 + 4] = r4;
  }
  __syncthreads();
  if (tid < 5) {
    float s = red[tid] + red[5 + tid] + red[10 + tid] + red[15 + tid];
    atomicAdd(&accs[tid], s);
  }
  __syncthreads();  // block's atomics retired before counting
  if (tid == 0) {
    u32* cnt = (u32*)(accs + 8);
    if (atomicAdd(cnt, 1u) == 511u) {  // last block finalizes
      float a0 = atomicAdd(&accs[0], 0.f);
      float a1 = atomicAdd(&accs[1], 0.f);
      float a2 = atomicAdd(&accs[2], 0.f);
      float a3 = atomicAdd(&accs[3], 0.f);
      float a4 = atomicAdd(&accs[4], 0.f);
      out[294912] = 0.001f * a0 * (1.0f / 262144.0f);
      out[294913] = -a1 * (1.0f / 32768.0f);
      out[294914] = -a2 * (1.0f / 32768.0f);
      out[294915] = -a3 * (1.0f / 32768.0f);
      out[294916] = -a4 * (1.0f / 32768.0f);
    }
  }
}

extern "C" void kernel_launch(void* const* d_in, const int* in_sizes, int n_in,
                              void* d_out, int out_size, void* d_ws, size_t ws_size,
                              hipStream_t stream) {
  const float* agent_qs = (const float*)d_in[0];
  const float* states   = (const float*)d_in[1];
  const int*   actions  = (const int*)d_in[2];
  const float* Wsel = (const float*)d_in[3];
  const float* Wkey = (const float*)d_in[4];
  const float* Wv1  = (const float*)d_in[5];
  const float* bv1  = (const float*)d_in[6];
  const float* Wv2  = (const float*)d_in[7];
  const float* bv2  = (const float*)d_in[8];
  const float* Wh   = (const float*)d_in[9];
  const float* bh   = (const float*)d_in[10];
  float* out = (float*)d_out;
  float* accs = (float*)d_ws;                    // 16 floats (incl. counter)
  u16* Wp = (u16*)((char*)d_ws + 64);            // 16 tiles x 400 x 32 bf16

  hipLaunchKernelGGL(kprep, dim3(136), dim3(256), 0, stream,
                     Wsel, Wkey, Wv1, Wh, Wp, accs);
  hipLaunchKernelGGL(kmain, dim3(512), dim3(256), 0, stream,
                     states, agent_qs, actions, Wp, bv1, Wv2, bv2, bh, out, accs);
}